// Round 3
// baseline (48503.516 us; speedup 1.0000x reference)
//
#include <hip/hip_runtime.h>
#include <stdint.h>

#define NB 250
#define NT 512
#define VOCAB 32000
#define EMB 512
#define HID 512
#define BATCH 32
#define SEQ 128

typedef unsigned long long u64;
typedef unsigned int u32;

// ---------------- ws layout (bytes) ----------------
// 0      : u32 gen                      (barrier release epoch)
// 64     : u64 packed[32]               argmax acc: key<<32 | (0xFFFFFFFF - v)
// 4096   : u32 arrive[NB*16]            per-block arrive flags, 64B stride
// 20480  : float h_ws[2][2][BATCH][HID] (layer, parity)
// 282624 : float c_ws[2][2][BATCH][HID]
// 544768 : float hT[HID][BATCH]         (layer-1 h, transposed, feeds dense)
// 610304 : end (~596 KB)

__device__ inline float sigf(float x) { return 1.0f / (1.0f + expf(-x)); }

__device__ inline u64 shfl_xor_u64(u64 v, int m) {
  u32 lo = (u32)v, hi = (u32)(v >> 32);
  lo = __shfl_xor(lo, m, 64);
  hi = __shfl_xor(hi, m, 64);
  return ((u64)hi << 32) | lo;
}

// Distributed grid barrier, monotonic epochs (no counter resets, no central
// RMW hotspot). Blocks 1..NB-1 publish arrive[bid]; block 0 polls all flags
// in parallel (one thread per flag, relaxed loads), then publishes gen.
// Works under PLAIN launch: 250 blocks x 8 waves are resident by capacity
// (8192-wave machine), so no block waits on an undispatched peer.
__device__ inline void grid_barrier(u32 epoch, u32* arrive, u32* gen) {
  __threadfence();   // release our data writes device-wide
  __syncthreads();
  int tid = threadIdx.x;
  if (blockIdx.x == 0) {
    if (tid >= 1 && tid < NB) {
      while (__hip_atomic_load(arrive + tid * 16, __ATOMIC_RELAXED,
                               __HIP_MEMORY_SCOPE_AGENT) < epoch) {
        __builtin_amdgcn_s_sleep(1);
      }
    }
    __syncthreads();
    if (tid == 0) {
      __hip_atomic_store(gen, epoch, __ATOMIC_RELAXED, __HIP_MEMORY_SCOPE_AGENT);
    }
  } else {
    if (tid == 0) {
      __hip_atomic_store(arrive + blockIdx.x * 16, epoch, __ATOMIC_RELAXED,
                         __HIP_MEMORY_SCOPE_AGENT);
      while (__hip_atomic_load(gen, __ATOMIC_RELAXED,
                               __HIP_MEMORY_SCOPE_AGENT) < epoch) {
        __builtin_amdgcn_s_sleep(1);
      }
    }
    __syncthreads();
  }
  __threadfence();   // acquire: no stale lines after exit
}

// Each thread contributes 8 candidates (one v, 8 consecutive b = bq*8+j).
// Reduce over the 16 v-lanes of the wave, then the 8 waves via LDS, then
// conditional device atomicMax into packed[b]. Low 32 bits hold
// (0xFFFFFFFF - v): equal keys pick smaller v (JAX first-occurrence).
__device__ inline void argmax_commit(const float* vals, int v, u64* cand, u64* packed) {
  int tid = threadIdx.x;
  u64 loc[8];
#pragma unroll
  for (int j = 0; j < 8; ++j) {
    u32 u = __float_as_uint(vals[j]);
    u32 key = (u & 0x80000000u) ? ~u : (u | 0x80000000u);  // monotonic float
    loc[j] = ((u64)key << 32) | (u64)(0xFFFFFFFFu - (u32)v);
  }
#pragma unroll
  for (int m = 4; m <= 32; m <<= 1) {
#pragma unroll
    for (int j = 0; j < 8; ++j) {
      u64 o = shfl_xor_u64(loc[j], m);
      if (o > loc[j]) loc[j] = o;
    }
  }
  int wave = tid >> 6, lane = tid & 63;
  if (lane < 4) {  // lane == bq for these lanes (vl bits reduced away)
#pragma unroll
    for (int j = 0; j < 8; ++j) cand[(wave * 4 + lane) * 8 + j] = loc[j];
  }
  __syncthreads();
  if (tid < 32) {  // tid == b ; b = bq*8 + j
    int bq = tid >> 3, j = tid & 7;
    u64 best = cand[bq * 8 + j];
#pragma unroll
    for (int w = 1; w < 8; ++w) {
      u64 c2 = cand[(w * 4 + bq) * 8 + j];
      if (c2 > best) best = c2;
    }
    u64 cur = packed[tid];  // stale-tolerant filter, cuts atomic traffic
    if (best > cur) atomicMax(packed + tid, best);
  }
  __syncthreads();
}

// One LSTM layer for one step. Blocks 0..127 active; block bid owns hidden
// units n in [bid*4, bid*4+4). Thread (jl,b): jl = g*4+nl over the 16 gate
// rows (PyTorch order i,f,g,o -> j = g*512 + n), b = batch row.
// Per-block weight slice is 64KB/layer and identical across steps -> L2-hot.
__device__ void lstm_phase(int layer, int parity, const float* emb, const u64* packed,
                           const float* W_ih, const float* W_hh,
                           const float* b_ih, const float* b_hh,
                           float* h_ws, float* c_ws, float* hT,
                           float (*g_lds)[33]) {
  int bid = blockIdx.x, tid = threadIdx.x;
  if (bid < 128) {
    int jl = tid >> 5, b = tid & 31;
    int g = jl >> 2, nl = jl & 3;
    int n = bid * 4 + nl;
    int j = g * 512 + n;
    const float* wi = W_ih + ((size_t)layer * 2048 + j) * EMB;
    const float* wh = W_hh + ((size_t)layer * 2048 + j) * HID;
    const float* xrow;
    if (layer == 0) {
      u64 p = packed[b];
      int idx = (int)(0xFFFFFFFFu - (u32)(p & 0xFFFFFFFFu));
      xrow = emb + (size_t)idx * EMB;  // embedding gather
    } else {
      xrow = h_ws + ((size_t)(0 * 2 + (parity ^ 1)) * BATCH + b) * HID;  // L0 new h
    }
    const float* hrow = h_ws + ((size_t)(layer * 2 + parity) * BATCH + b) * HID;
    float a0 = 0.f, a1 = 0.f, a2 = 0.f, a3 = 0.f;
    for (int k = 0; k < 512; k += 8) {
      float4 xa = *(const float4*)(xrow + k);
      float4 xb = *(const float4*)(xrow + k + 4);
      float4 wa = *(const float4*)(wi + k);
      float4 wb = *(const float4*)(wi + k + 4);
      float4 ha = *(const float4*)(hrow + k);
      float4 hb = *(const float4*)(hrow + k + 4);
      float4 ua = *(const float4*)(wh + k);
      float4 ub = *(const float4*)(wh + k + 4);
      a0 = fmaf(xa.x, wa.x, a0); a1 = fmaf(xa.y, wa.y, a1);
      a2 = fmaf(xa.z, wa.z, a2); a3 = fmaf(xa.w, wa.w, a3);
      a0 = fmaf(xb.x, wb.x, a0); a1 = fmaf(xb.y, wb.y, a1);
      a2 = fmaf(xb.z, wb.z, a2); a3 = fmaf(xb.w, wb.w, a3);
      a0 = fmaf(ha.x, ua.x, a0); a1 = fmaf(ha.y, ua.y, a1);
      a2 = fmaf(ha.z, ua.z, a2); a3 = fmaf(ha.w, ua.w, a3);
      a0 = fmaf(hb.x, ub.x, a0); a1 = fmaf(hb.y, ub.y, a1);
      a2 = fmaf(hb.z, ub.z, a2); a3 = fmaf(hb.w, ub.w, a3);
    }
    float gate = (a0 + a1) + (a2 + a3)
               + b_ih[layer * 2048 + j] + b_hh[layer * 2048 + j];
    g_lds[jl][b] = gate;
  }
  __syncthreads();
  if (bid < 128 && tid < 128) {
    int nl = tid >> 5, b = tid & 31;
    int n = bid * 4 + nl;
    float iv = sigf(g_lds[nl][b]);
    float fv = sigf(g_lds[4 + nl][b]);
    float gv = tanhf(g_lds[8 + nl][b]);
    float ov = sigf(g_lds[12 + nl][b]);
    size_t cold_off = ((size_t)(layer * 2 + parity) * BATCH + b) * HID + n;
    size_t cnew_off = ((size_t)(layer * 2 + (parity ^ 1)) * BATCH + b) * HID + n;
    float c_old = c_ws[cold_off];
    float c_new = fv * c_old + iv * gv;
    float h_new = ov * tanhf(c_new);
    c_ws[cnew_off] = c_new;
    h_ws[cnew_off] = h_new;
    if (layer == 1) hT[(size_t)n * BATCH + b] = h_new;  // transposed feed for dense
  }
}

// Dense projection + output store + fused argmax. Block bid owns v-rows
// [bid*128, bid*128+128). Thread (vl,bq): one v row, 8 batch accumulators.
__device__ void dense_phase(int t, const float* hT, const float* Wd, const float* bd,
                            float* out, u64* cand, u64* packed) {
  int bid = blockIdx.x, tid = threadIdx.x;
  int vl = tid >> 2, bq = tid & 3;
  int v = bid * 128 + vl;
  int b0 = bq * 8;
  const float* wrow = Wd + (size_t)v * HID;
  float bias = bd[v];
  float acc[8] = {0.f, 0.f, 0.f, 0.f, 0.f, 0.f, 0.f, 0.f};
  for (int k = 0; k < HID; k += 4) {
    float4 w4 = *(const float4*)(wrow + k);
    float wv[4] = {w4.x, w4.y, w4.z, w4.w};
#pragma unroll
    for (int i = 0; i < 4; ++i) {
      const float* Ak = hT + (size_t)(k + i) * BATCH + b0;
      float4 p0 = *(const float4*)(Ak);
      float4 p1 = *(const float4*)(Ak + 4);
      acc[0] = fmaf(wv[i], p0.x, acc[0]);
      acc[1] = fmaf(wv[i], p0.y, acc[1]);
      acc[2] = fmaf(wv[i], p0.z, acc[2]);
      acc[3] = fmaf(wv[i], p0.w, acc[3]);
      acc[4] = fmaf(wv[i], p1.x, acc[4]);
      acc[5] = fmaf(wv[i], p1.y, acc[5]);
      acc[6] = fmaf(wv[i], p1.z, acc[6]);
      acc[7] = fmaf(wv[i], p1.w, acc[7]);
    }
  }
  size_t obase = (size_t)t * VOCAB + v;
#pragma unroll
  for (int j = 0; j < 8; ++j) {
    acc[j] += bias;
    // Streaming 524MB total output: nontemporal keeps Wd resident in cache.
    __builtin_nontemporal_store(acc[j],
        &out[(size_t)(b0 + j) * ((size_t)SEQ * VOCAB) + obase]);
  }
  argmax_commit(acc, v, cand, packed);
}

// Copy h0/c0 into parity-0 state and compute argmax of the input logits x.
__device__ void init_phase(const float* x, const float* h0, const float* c0,
                           float* h_ws, float* c_ws, u64* cand, u64* packed) {
  int bid = blockIdx.x, tid = threadIdx.x;
  int gidx = bid * NT + tid;
  if (gidx < 8192) {                        // h0: 32768 floats = 8192 float4
    int l = gidx >> 12, rem = gidx & 4095;  // 4096 float4 per layer (parity 0)
    ((float4*)h_ws)[l * 8192 + rem] = ((const float4*)h0)[gidx];
  } else if (gidx < 16384) {                // c0
    int f = gidx - 8192;
    int l = f >> 12, rem = f & 4095;
    ((float4*)c_ws)[l * 8192 + rem] = ((const float4*)c0)[f];
  }
  int vl = tid >> 2, bq = tid & 3;
  int v = bid * 128 + vl;
  float vals[8];
#pragma unroll
  for (int j = 0; j < 8; ++j) vals[j] = x[(size_t)(bq * 8 + j) * VOCAB + v];
  argmax_commit(vals, v, cand, packed);
}

__global__ __launch_bounds__(NT, 1) void lstm_dec_kernel(
    const float* x, const float* h0, const float* c0, const float* emb,
    const float* W_ih, const float* W_hh, const float* b_ih, const float* b_hh,
    const float* Wd, const float* bd, float* out, char* ws) {
  u32* gen    = (u32*)ws;
  u64* packed = (u64*)(ws + 64);
  u32* arrive = (u32*)(ws + 4096);
  float* h_ws = (float*)(ws + 20480);
  float* c_ws = (float*)(ws + 282624);
  float* hT   = (float*)(ws + 544768);
  __shared__ float g_lds[16][33];
  __shared__ u64 cand[256];

  u32 ep = 0;
  init_phase(x, h0, c0, h_ws, c_ws, cand, packed);
  grid_barrier(++ep, arrive, gen);

  for (int t = 0; t < SEQ; ++t) {
    int p = t & 1;
    // phase 1: LSTM layer 0 (reads packed -> embedding gather)
    lstm_phase(0, p, emb, packed, W_ih, W_hh, b_ih, b_hh, h_ws, c_ws, hT, g_lds);
    grid_barrier(++ep, arrive, gen);
    // phase 2: LSTM layer 1; block0 resets packed for this step's dense argmax
    lstm_phase(1, p, emb, packed, W_ih, W_hh, b_ih, b_hh, h_ws, c_ws, hT, g_lds);
    if (blockIdx.x == 0 && threadIdx.x < 32)
      __hip_atomic_store(&packed[threadIdx.x], 0ull, __ATOMIC_RELAXED,
                         __HIP_MEMORY_SCOPE_AGENT);
    grid_barrier(++ep, arrive, gen);
    // phase 3: dense projection + store ys[t] + fused argmax
    dense_phase(t, hT, Wd, bd, out, cand, packed);
    grid_barrier(++ep, arrive, gen);
  }
}

// Zero gen, packed, arrive flags (bytes 0..20480) every call — the harness
// re-poisons d_ws with 0xAA before each timed launch.
__global__ void zero_ctrl(u32* w) {
  int i = blockIdx.x * blockDim.x + threadIdx.x;
  if (i < 5120) w[i] = 0u;
}

extern "C" void kernel_launch(void* const* d_in, const int* in_sizes, int n_in,
                              void* d_out, int out_size, void* d_ws, size_t ws_size,
                              hipStream_t stream) {
  const float* x    = (const float*)d_in[0];
  const float* h0   = (const float*)d_in[1];
  const float* c0   = (const float*)d_in[2];
  const float* emb  = (const float*)d_in[3];
  const float* W_ih = (const float*)d_in[4];
  const float* W_hh = (const float*)d_in[5];
  const float* b_ih = (const float*)d_in[6];
  const float* b_hh = (const float*)d_in[7];
  const float* Wd   = (const float*)d_in[8];
  const float* bd   = (const float*)d_in[9];
  float* out = (float*)d_out;
  char* ws = (char*)d_ws;

  hipLaunchKernelGGL(zero_ctrl, dim3(10), dim3(512), 0, stream, (u32*)ws);

  // Plain launch (NOT cooperative): graph-capture-safe, and 250 blocks x 8
  // waves with tiny LDS/VGPR are resident by capacity on a 256-CU /
  // 8192-wave machine, so the software grid barrier cannot deadlock.
  hipLaunchKernelGGL(lstm_dec_kernel, dim3(NB), dim3(NT), 0, stream,
                     x, h0, c0, emb, W_ih, W_hh, b_ih, b_hh, Wd, bd, out, ws);
}